// Round 15
// baseline (212.820 us; speedup 1.0000x reference)
//
#include <hip/hip_runtime.h>
#include <hip/hip_fp16.h>
#include <stdint.h>

// Problem constants (B=8, N=2048, F=512, A=512)
#define B_   8
#define N_   2048
#define F_   512
#define A_   512
#define MTOT (B_ * N_)   // 16384 rows total

typedef unsigned short u16;
typedef unsigned int   u32;
typedef __attribute__((ext_vector_type(8))) __bf16    bf16x8;
typedef __attribute__((ext_vector_type(8))) _Float16  f16x8;
typedef __attribute__((ext_vector_type(4))) float     f32x4;

// ---------- scalar converts ----------
__device__ __forceinline__ u16 f2bf(float f) {   // RNE
    u32 u = __builtin_bit_cast(u32, f);
    u32 r = u + 0x7fffu + ((u >> 16) & 1u);
    return (u16)(r >> 16);
}
__device__ __forceinline__ float bf2f(u16 h) {
    return __builtin_bit_cast(float, (u32)h << 16);
}
__device__ __forceinline__ u16 f2h(float f) {    // RNE via HW cvt
    _Float16 h = (_Float16)f;
    return __builtin_bit_cast(u16, h);
}

// async global->LDS, 16B per lane (linear lane-ordered dest)
__device__ __forceinline__ void gload_lds16(const u16* g, u16* l) {
    __builtin_amdgcn_global_load_lds(
        (const __attribute__((address_space(1))) u32*)(const u32*)g,
        (__attribute__((address_space(3))) u32*)(u32*)l,
        16, 0, 0);
}

#define VMCNT(n) asm volatile("s_waitcnt vmcnt(" #n ")" ::: "memory")
#define LGKM0()  asm volatile("s_waitcnt lgkmcnt(0)" ::: "memory")
#define SCHEDB() __builtin_amdgcn_sched_barrier(0)

__device__ __forceinline__ void sync_pre() {
    SCHEDB();
    __builtin_amdgcn_s_barrier();
    LGKM0();
    SCHEDB();
}
__device__ __forceinline__ void sync_post() {
    SCHEDB();
    __builtin_amdgcn_s_barrier();
}

// ---------- merged prep: x->fp16, weights->fp16/bf16, bias concat, zeroing ----
__global__ __launch_bounds__(256)
void prep_all(const float* __restrict__ x,
              const float* __restrict__ Wq, const float* __restrict__ Wk,
              const float* __restrict__ Wv, const float* __restrict__ Wo,
              const float* __restrict__ bq, const float* __restrict__ bk,
              u16* __restrict__ xh,
              u16* __restrict__ wqkh, u16* __restrict__ wvh, u16* __restrict__ wob,
              float* __restrict__ bqk, float* __restrict__ stats)
{
    int b = blockIdx.x, t = threadIdx.x;
    if (b < 8192) {                       // x -> fp16
        int i = b * 256 + t;
        float4 v = ((const float4*)x)[i];
        u32 a = (u32)f2h(v.x) | ((u32)f2h(v.y) << 16);
        u32 c = (u32)f2h(v.z) | ((u32)f2h(v.w) << 16);
        ((uint2*)xh)[i] = make_uint2(a, c);
    } else if (b < 9216) {                // weights
        int bb = b - 8192;
        int i = (bb & 255) * 256 + t;
        int seg = bb >> 8;                // 0 Wq, 1 Wk, 2 Wv, 3 Wo
        const float* src = seg == 0 ? Wq : seg == 1 ? Wk : seg == 2 ? Wv : Wo;
        u16* dst = seg == 0 ? wqkh : seg == 1 ? (wqkh + 262144)
                                   : seg == 2 ? wvh : wob;
        float4 v = ((const float4*)src)[i];
        u32 a, c;
        if (seg < 3) {
            a = (u32)f2h(v.x) | ((u32)f2h(v.y) << 16);
            c = (u32)f2h(v.z) | ((u32)f2h(v.w) << 16);
        } else {
            a = (u32)f2bf(v.x) | ((u32)f2bf(v.y) << 16);
            c = (u32)f2bf(v.z) | ((u32)f2bf(v.w) << 16);
        }
        ((uint2*)dst)[i] = make_uint2(a, c);
        if (bb == 0 && t < 128) ((float4*)bqk)[t]         = ((const float4*)bq)[t];
        if (bb == 1 && t < 128) ((float4*)(bqk + 512))[t] = ((const float4*)bk)[t];
    } else {                              // zero stats + rowsum (80 KB)
        int i = (b - 9216) * 256 + t;
        ((float4*)stats)[i] = make_float4(0.f, 0.f, 0.f, 0.f);
    }
}

// ============ 8-phase pipelined NT GEMM (r6/r9 structure, proven best) ============
// BM=256, BK=64, 8 waves (2M x 4N). BN: 256 (4 phases) or 128 (2 phases).
// EPI: 0 none; 1 store bf16(exp(v)) + atomicAdd rowsum into aux[z*N_+m];
//      2 BN-stats atomics into aux; 3 row-scale v *= 1/aux[m].
// XS:  0 none; 1 swap blockIdx x<->z (QK^T: XCD=batch);
//      2 remap bx=((bx&7)<<3)|(bx>>3)  (only valid for 64-block grids).
template <int BN, int BIAS_MODE, int OUT_FMT, int IN_FMT, int EPI, int XS>
__global__ __launch_bounds__(512, 2)
void gemm8(const u16* __restrict__ A, int lda, long sA,
           const u16* __restrict__ Bm, int ldb, long sB,
           const float* __restrict__ bias,
           void* __restrict__ Cv, int ldc, long sC, int K, int bdiag,
           float* __restrict__ aux)
{
    constexpr int UNITS = (BN == 256) ? 4 : 3;
    constexpr int NF = BN / 64;
    __shared__ alignas(16) u16 lds[2 * UNITS * 8192];

    int bx = blockIdx.x, bz = blockIdx.z;
    if constexpr (XS == 1) { int tt = bx; bx = bz; bz = tt; }
    if constexpr (XS == 2) { bx = ((bx & 7) << 3) | (bx >> 3); }
    const int z  = bz;
    const int m0 = bx * 256;
    const int n0 = blockIdx.y * BN;
    const u16* Ag = A  + (long)z * sA + (long)m0 * lda;
    const u16* Bg = Bm + (long)z * sB + (long)n0 * ldb + (long)(m0 >> 11) * bdiag;

    const int t = threadIdx.x;
    const int lane = t & 63;
    const int wave = t >> 6;
    const int wm = wave >> 2, wn = wave & 3;
    const int frow = lane & 15;
    const int fk8 = (lane >> 4) * 8;

    const int srr = t >> 3;
    const int ses = ((t & 7) * 8) ^ ((srr & 7) << 3);

    auto stageA = [&](int buf, int h, int kt) {
        u16* dst = &lds[(buf * UNITS + h) * 8192 + t * 8];
        const u16* g = Ag + kt * 64 + ses;
        gload_lds16(g + (long)(srr + h * 64) * lda,        dst);
        gload_lds16(g + (long)(srr + 128 + h * 64) * lda,  dst + 4096);
    };
    auto stageB = [&](int buf, int h, int kt) {
        u16* dst = &lds[(buf * UNITS + 2 + h) * 8192 + t * 8];
        const u16* g = Bg + kt * 64 + ses;
        int R0;
        if constexpr (BN == 256) R0 = (srr & 31) + ((srr >> 5) << 6) + h * 32;
        else                     R0 = srr;
        int R1 = R0 + ((BN == 256) ? 128 : 64);
        gload_lds16(g + (long)R0 * ldb, dst);
        gload_lds16(g + (long)R1 * ldb, dst + 4096);
    };
    auto rdA = [&](int buf, int q, int i, int ks) -> uint4 {
        int rr = wm * 64 + i * 16 + frow;
        int e  = (ks * 32 + fk8) ^ ((rr & 7) << 3);
        return *(const uint4*)&lds[(buf * UNITS + q) * 8192 + rr * 64 + e];
    };
    auto rdB = [&](int buf, int p, int j, int ks) -> uint4 {
        int rr = wn * 32 + j * 16 + frow;
        int e  = (ks * 32 + fk8) ^ ((rr & 7) << 3);
        return *(const uint4*)&lds[(buf * UNITS + 2 + p) * 8192 + rr * 64 + e];
    };
    auto MF = [&](uint4 a, uint4 b, f32x4 c) -> f32x4 {
        if constexpr (IN_FMT == 0)
            return __builtin_amdgcn_mfma_f32_16x16x32_bf16(
                __builtin_bit_cast(bf16x8, a), __builtin_bit_cast(bf16x8, b), c, 0, 0, 0);
        else
            return __builtin_amdgcn_mfma_f32_16x16x32_f16(
                __builtin_bit_cast(f16x8, a), __builtin_bit_cast(f16x8, b), c, 0, 0, 0);
    };

    f32x4 acc[8][NF];
#pragma unroll
    for (int i = 0; i < 8; i++)
#pragma unroll
        for (int j = 0; j < NF; j++)
#pragma unroll
            for (int r = 0; r < 4; r++) acc[i][j][r] = 0.f;

    uint4 fa[4][2], fb0[2][2], fb1[2][2];
    const int NT = K >> 6;

    if constexpr (BN == 256) {
        stageA(0, 0, 0); stageB(0, 0, 0); stageB(0, 1, 0); stageA(0, 1, 0);
        VMCNT(4);
    } else {
        stageA(0, 0, 0); stageB(0, 0, 0); stageA(0, 1, 0);
        VMCNT(2);
    }
    SCHEDB();
    __builtin_amdgcn_s_barrier();

    for (int kt = 0; kt < NT; ++kt) {
        const int buf = kt & 1, nb = buf ^ 1;
        const bool st = (kt + 1 < NT);

        if constexpr (BN == 256) {
#pragma unroll
            for (int i = 0; i < 4; i++) { fa[i][0] = rdA(buf, 0, i, 0); fa[i][1] = rdA(buf, 0, i, 1); }
#pragma unroll
            for (int j = 0; j < 2; j++) { fb0[j][0] = rdB(buf, 0, j, 0); fb0[j][1] = rdB(buf, 0, j, 1); }
            if (st) { stageA(nb, 0, kt + 1); VMCNT(4); } else VMCNT(2);
            sync_pre();
            __builtin_amdgcn_s_setprio(1);
#pragma unroll
            for (int ks = 0; ks < 2; ks++)
#pragma unroll
                for (int i = 0; i < 4; i++)
#pragma unroll
                    for (int j = 0; j < 2; j++)
                        acc[i][j] = MF(fa[i][ks], fb0[j][ks], acc[i][j]);
            __builtin_amdgcn_s_setprio(0);
            sync_post();
#pragma unroll
            for (int j = 0; j < 2; j++) { fb1[j][0] = rdB(buf, 1, j, 0); fb1[j][1] = rdB(buf, 1, j, 1); }
            if (st) { stageB(nb, 0, kt + 1); VMCNT(4); } else VMCNT(0);
            sync_pre();
            __builtin_amdgcn_s_setprio(1);
#pragma unroll
            for (int ks = 0; ks < 2; ks++)
#pragma unroll
                for (int i = 0; i < 4; i++)
#pragma unroll
                    for (int j = 0; j < 2; j++)
                        acc[i][2 + j] = MF(fa[i][ks], fb1[j][ks], acc[i][2 + j]);
            __builtin_amdgcn_s_setprio(0);
            sync_post();
#pragma unroll
            for (int i = 0; i < 4; i++) { fa[i][0] = rdA(buf, 1, i, 0); fa[i][1] = rdA(buf, 1, i, 1); }
            if (st) stageB(nb, 1, kt + 1);
            sync_pre();
            __builtin_amdgcn_s_setprio(1);
#pragma unroll
            for (int ks = 0; ks < 2; ks++)
#pragma unroll
                for (int i = 0; i < 4; i++)
#pragma unroll
                    for (int j = 0; j < 2; j++)
                        acc[4 + i][j] = MF(fa[i][ks], fb0[j][ks], acc[4 + i][j]);
            __builtin_amdgcn_s_setprio(0);
            sync_post();
            if (st) { stageA(nb, 1, kt + 1); VMCNT(4); }
            sync_pre();
            __builtin_amdgcn_s_setprio(1);
#pragma unroll
            for (int ks = 0; ks < 2; ks++)
#pragma unroll
                for (int i = 0; i < 4; i++)
#pragma unroll
                    for (int j = 0; j < 2; j++)
                        acc[4 + i][2 + j] = MF(fa[i][ks], fb1[j][ks], acc[4 + i][2 + j]);
            __builtin_amdgcn_s_setprio(0);
            sync_post();
        } else {
#pragma unroll
            for (int i = 0; i < 4; i++) { fa[i][0] = rdA(buf, 0, i, 0); fa[i][1] = rdA(buf, 0, i, 1); }
#pragma unroll
            for (int j = 0; j < 2; j++) { fb0[j][0] = rdB(buf, 0, j, 0); fb0[j][1] = rdB(buf, 0, j, 1); }
            if (st) { stageA(nb, 0, kt + 1); stageB(nb, 0, kt + 1); VMCNT(4); } else VMCNT(0);
            sync_pre();
            __builtin_amdgcn_s_setprio(1);
#pragma unroll
            for (int ks = 0; ks < 2; ks++)
#pragma unroll
                for (int i = 0; i < 4; i++)
#pragma unroll
                    for (int j = 0; j < 2; j++)
                        acc[i][j] = MF(fa[i][ks], fb0[j][ks], acc[i][j]);
            __builtin_amdgcn_s_setprio(0);
            sync_post();
#pragma unroll
            for (int i = 0; i < 4; i++) { fa[i][0] = rdA(buf, 1, i, 0); fa[i][1] = rdA(buf, 1, i, 1); }
            if (st) { stageA(nb, 1, kt + 1); VMCNT(2); }
            sync_pre();
            __builtin_amdgcn_s_setprio(1);
#pragma unroll
            for (int ks = 0; ks < 2; ks++)
#pragma unroll
                for (int i = 0; i < 4; i++)
#pragma unroll
                    for (int j = 0; j < 2; j++)
                        acc[4 + i][j] = MF(fa[i][ks], fb0[j][ks], acc[4 + i][j]);
            __builtin_amdgcn_s_setprio(0);
            sync_post();
        }
    }

    const int rq = (lane >> 4) * 4;
#pragma unroll
    for (int am = 0; am < 8; am++) {
        const int m = m0 + wm * 128 + (am >> 2) * 64 + (am & 3) * 16 + rq;
#pragma unroll
        for (int r = 0; r < 4; r++) {
            float rscale = 1.f;
            if constexpr (EPI == 3) rscale = 1.0f / aux[m + r];
            float se = 0.f, s1 = 0.f, s2 = 0.f;
#pragma unroll
            for (int an = 0; an < NF; an++) {
                const int n = n0 + wn * (BN / 4) + an * 16 + frow;
                float v = acc[am][an][r];
                if (BIAS_MODE == 1) v += bias[n];
                if (BIAS_MODE == 2) v += bias[m + r];
                if constexpr (EPI == 1) { v = __expf(v); se += v; }
                if constexpr (EPI == 3) { v *= rscale; }
                if constexpr (EPI == 2) { s1 += v; s2 += v * v; }
                long idx = (long)(m + r) * ldc + n + (long)z * sC;
                if constexpr (OUT_FMT == 0)      ((u16*)Cv)[idx] = f2bf(v);
                else if constexpr (OUT_FMT == 1) ((float*)Cv)[idx] = v;
                else                             ((u16*)Cv)[idx] = f2h(v);
            }
            if constexpr (EPI == 1) {
#pragma unroll
                for (int o = 1; o < 16; o <<= 1) se += __shfl_xor(se, o);
                if (frow == 0)
                    atomicAdd(&aux[(long)z * N_ + m + r], se);
            }
            if constexpr (EPI == 2) {
#pragma unroll
                for (int o = 1; o < 16; o <<= 1) { s1 += __shfl_xor(s1, o); s2 += __shfl_xor(s2, o); }
                if (frow == 0) {
                    int tok = (m + r) & (N_ - 1);
                    atomicAdd(&aux[tok], s1);
                    atomicAdd(&aux[N_ + tok], s2);
                }
            }
        }
    }
}

// ============ PV GEMM: r4 m97-structure (multi-block/CU) + swizzle + fusions ====
// feat[m][n] = (P[m][:] @ vt[n][batch*2048+:]) / rowsum[m]
// 128x128 tile, BK=64, 4 waves (2x2), 32 KB LDS single-buffer, 2 barriers/tile.
// Long K (NT=32) + multi-block/CU -> implicit wave-level overlap across blocks.
__global__ __launch_bounds__(256)
void gemm_pv(const u16* __restrict__ P, const u16* __restrict__ vt,
             const float* __restrict__ rowsum, u16* __restrict__ feat)
{
    __shared__ alignas(16) u16 lA[128 * 64];
    __shared__ alignas(16) u16 lB[128 * 64];

    int bx = blockIdx.x;
    // BIJECTIVE remap on [0,128): XCD = bx&7 owns 16 contiguous m-tiles
    // (= one full batch -> its 2 MB vt slice is L2-resident).
    bx = ((bx & 7) << 4) | (bx >> 3);
    const int m0 = bx * 128;
    const int n0 = blockIdx.y * 128;
    const int batch = m0 >> 11;
    const u16* Ag = P  + (long)m0 * N_;
    const u16* Bg = vt + (long)n0 * MTOT + batch * N_;

    const int t = threadIdx.x;
    const int lane = t & 63, wave = t >> 6;
    const int wr = (wave >> 1) * 64;
    const int wc = (wave & 1) * 64;
    const int frow = lane & 15;
    const int fk = (lane >> 4) * 8;

    f32x4 acc[4][4];
#pragma unroll
    for (int i = 0; i < 4; i++)
#pragma unroll
        for (int j = 0; j < 4; j++)
#pragma unroll
            for (int r = 0; r < 4; r++) acc[i][j][r] = 0.f;

    const int srow = t >> 3;                             // 0..31
    const int ses  = ((t & 7) * 8) ^ ((srow & 7) << 3);  // pre-swizzled src col

    for (int kt = 0; kt < N_; kt += 64) {
        __syncthreads();
#pragma unroll
        for (int s = 0; s < 4; ++s) {
            int row = s * 32 + srow;
            gload_lds16(Ag + (long)row * N_   + kt + ses, &lA[s * 2048 + t * 8]);
            gload_lds16(Bg + (long)row * MTOT + kt + ses, &lB[s * 2048 + t * 8]);
        }
        __syncthreads();
#pragma unroll
        for (int kk = 0; kk < 64; kk += 32) {
            uint4 ar[4], br[4];
#pragma unroll
            for (int i = 0; i < 4; i++) {
                int rr = wr + i * 16 + frow;
                ar[i] = *(const uint4*)&lA[rr * 64 + ((kk + fk) ^ ((rr & 7) << 3))];
            }
#pragma unroll
            for (int j = 0; j < 4; j++) {
                int rr = wc + j * 16 + frow;
                br[j] = *(const uint4*)&lB[rr * 64 + ((kk + fk) ^ ((rr & 7) << 3))];
            }
#pragma unroll
            for (int i = 0; i < 4; i++)
#pragma unroll
                for (int j = 0; j < 4; j++)
                    acc[i][j] = __builtin_amdgcn_mfma_f32_16x16x32_bf16(
                        __builtin_bit_cast(bf16x8, ar[i]),
                        __builtin_bit_cast(bf16x8, br[j]), acc[i][j], 0, 0, 0);
        }
    }

    // epilogue: C/D col = lane&15, row = (lane>>4)*4 + r; scale by 1/rowsum
    const int rbase = (lane >> 4) * 4;
#pragma unroll
    for (int i = 0; i < 4; i++) {
        int m = m0 + wr + i * 16 + rbase;
#pragma unroll
        for (int r = 0; r < 4; r++) {
            float rscale = 1.0f / rowsum[m + r];
#pragma unroll
            for (int j = 0; j < 4; j++) {
                int n = n0 + wc + j * 16 + frow;
                feat[(long)(m + r) * A_ + n] = f2bf(acc[i][j][r] * rscale);
            }
        }
    }
}

// ---------- BN apply (from accumulated sums) + ReLU + residual ----------
__global__ __launch_bounds__(256)
void bn_relu_add(const u16* __restrict__ linb, const u16* __restrict__ xh,
                 const float* __restrict__ gamma, const float* __restrict__ beta,
                 const float* __restrict__ stats, float* __restrict__ out) {
    long i4 = (long)blockIdx.x * 256 + threadIdx.x;
    int n = (int)((i4 >> 7) & (N_ - 1));
    float mean = stats[n] * (1.f / 4096.f);
    float var  = stats[N_ + n] * (1.f / 4096.f) - mean * mean;
    float rstd = rsqrtf(var + 1e-5f);
    float scale = gamma[n] * rstd;
    float shift = beta[n] - mean * scale;
    uint2 lb = ((const uint2*)linb)[i4];
    uint2 xb = ((const uint2*)xh)[i4];
    float2 x01 = __half22float2(__builtin_bit_cast(__half2, xb.x));
    float2 x23 = __half22float2(__builtin_bit_cast(__half2, xb.y));
    float4 o;
    o.x = fmaxf(bf2f((u16)lb.x)         * scale + shift, 0.f) + x01.x;
    o.y = fmaxf(bf2f((u16)(lb.x >> 16)) * scale + shift, 0.f) + x01.y;
    o.z = fmaxf(bf2f((u16)lb.y)         * scale + shift, 0.f) + x23.x;
    o.w = fmaxf(bf2f((u16)(lb.y >> 16)) * scale + shift, 0.f) + x23.y;
    ((float4*)out)[i4] = o;
}

extern "C" void kernel_launch(void* const* d_in, const int* in_sizes, int n_in,
                              void* d_out, int out_size, void* d_ws, size_t ws_size,
                              hipStream_t stream)
{
    (void)in_sizes; (void)n_in; (void)out_size; (void)ws_size;
    const float* x     = (const float*)d_in[0];
    const float* Wq    = (const float*)d_in[1];
    const float* bq    = (const float*)d_in[2];
    const float* Wk    = (const float*)d_in[3];
    const float* bk    = (const float*)d_in[4];
    const float* Wv    = (const float*)d_in[5];
    const float* bv    = (const float*)d_in[6];
    const float* Wo    = (const float*)d_in[7];
    const float* bo    = (const float*)d_in[8];
    const float* gamma = (const float*)d_in[9];
    const float* beta  = (const float*)d_in[10];
    float* out = (float*)d_out;
    char*  ws  = (char*)d_ws;

    const size_t MB = 1024 * 1024;
    u16*   wqkh  = (u16*)(ws + 0);                    // fp16 [1024][512]: Wq | Wk
    u16*   wvh   = (u16*)(ws + 1 * MB);               // fp16 [512][512]
    u16*   wob   = (u16*)(ws + 1 * MB + 512 * 1024);  // bf16 [512][512]
    float* stats = (float*)(ws + 2 * MB);             // 16 KB {sum, sumsq} per token
    float* rowsum= (float*)(ws + 2 * MB + 16 * 1024); // 64 KB sum(exp) per Q-row
    float* bqk   = (float*)(ws + 2 * MB + 80 * 1024); // fp32 [1024]
    u16*   xh    = (u16*)(ws + 4 * MB);               // 16 MB fp16 [16384][512]
    u16*   qkh   = (u16*)(ws + 20 * MB);              // 32 MB fp16 [16384][1024]
    u16*   vt    = (u16*)(ws + 52 * MB);              // 16 MB bf16 [512][16384]
    u16*   P     = (u16*)(ws + 68 * MB);              // 64 MB bf16 exp(scores)
    u16*   feat  = (u16*)(ws + 132 * MB);             // 16 MB bf16
    u16*   lin   = (u16*)(ws + 148 * MB);             // 16 MB bf16

    // one merged prep dispatch
    prep_all<<<9236, 256, 0, stream>>>(x, Wq, Wk, Wv, Wo, bq, bk,
                                       xh, wqkh, wvh, wob, bqk, stats);

    // [q|k] = x @ [Wq|Wk]^T + bqk   (M=16384, N=1024, K=512) fp16
    gemm8<256, 1, 2, 1, 0, 0><<<dim3(64, 4, 1), 512, 0, stream>>>(
        xh, 512, 0, wqkh, 512, 0, bqk, qkh, 1024, 0, 512, 0, nullptr);
    // v^T = Wv @ x^T + bv(row)   (M=512, N=16384, K=512) -> vt[a][token] bf16
    gemm8<128, 2, 0, 1, 0, 0><<<dim3(2, 128, 1), 512, 0, stream>>>(
        wvh, 512, 0, xh, 512, 0, bv, vt, MTOT, 0, 512, 0, nullptr);
    // P = exp(q @ k^T) + rowsum atomics  (XCD=batch via XS=1)
    gemm8<256, 0, 0, 1, 1, 1><<<dim3(8, 8, 8), 512, 0, stream>>>(
        qkh, 1024, (long)N_ * 1024, qkh + 512, 1024, (long)N_ * 1024,
        nullptr, P, N_, (long)N_ * N_, 512, 0, rowsum);
    // feat = (P @ v) / rowsum   (r4 multi-block structure + swizzle; XCD=batch)
    gemm_pv<<<dim3(128, 4, 1), 256, 0, stream>>>(P, vt, rowsum, feat);
    // lin = feat @ Wo^T + bo  (bf16 out) + fused per-token BN sums
    gemm8<128, 1, 0, 0, 2, 0><<<dim3(64, 4, 1), 512, 0, stream>>>(
        feat, 512, 0, wob, 512, 0, bo, lin, 512, 0, 512, 0, stats);

    bn_relu_add<<<8192, 256, 0, stream>>>(lin, xh, gamma, beta, stats, out);
}